// Round 5
// baseline (682.833 us; speedup 1.0000x reference)
//
#include <hip/hip_runtime.h>
#include <math.h>

#define Bsz 32
#define Tt  10
#define Dd  10
#define Uu  50
#define Pp  50
#define Ee  256

typedef __attribute__((ext_vector_type(8))) short bf16x8;   // MFMA A/B frag
typedef __attribute__((ext_vector_type(4))) float f32x4;    // MFMA C/D frag

#define STH 264   // sH row stride (halfwords): 256+8, 16B-aligned rows
#define STV 72    // sVt row stride
#define STS 72    // sS row stride

// kernel1 (attention) LDS: sVt 256x72x2=36864 | sS 64x72x2=9216 | red 1024
#define K1_OFF_V 0
#define K1_OFF_S 36864
#define K1_OFF_R 46080
#define K1_SMEM  47104   // 3 blocks/CU

// kernel2 (FFN, flat-M GEMM) LDS: sH 128x264x2=67584 | red2 128*4*2*4=4096
#define K2_OFF_H 0
#define K2_OFF_R 67584
#define K2_SMEM  71680   // 2 blocks/CU (143,360 <= 163,840)
#define FFN_BM 128

__device__ __forceinline__ unsigned short f2bf(float f) {      // RNE fp32->bf16
    unsigned u = __builtin_bit_cast(unsigned, f);
    u += 0x7fffu + ((u >> 16) & 1u);
    return (unsigned short)(u >> 16);
}
__device__ __forceinline__ float bf2f(unsigned short h) {
    unsigned u = ((unsigned)h) << 16;
    return __builtin_bit_cast(float, u);
}
// A/B fragment from LDS: lane q*16+l15 -> row r0+l15, cols c0+q*8..+7 (b128)
__device__ __forceinline__ bf16x8 ldfrag(const unsigned short* p, int stride, int r0, int c0, int lane) {
    return *(const bf16x8*)(p + (size_t)(r0 + (lane & 15)) * stride + c0 + ((lane >> 4) << 3));
}
// fragment from global fp32 row-major [row][256], row clamped at 49 (attn padding rows)
__device__ __forceinline__ bf16x8 gfrag49(const float* __restrict__ base, int n, int k0, int lane) {
    int row = n + (lane & 15);
    row = row > 49 ? 49 : row;
    const int col = k0 + ((lane >> 4) << 3);
    const float4 a = *(const float4*)(base + (size_t)row * 256 + col);
    const float4 b = *(const float4*)(base + (size_t)row * 256 + col + 4);
    bf16x8 r;
    r[0] = (short)f2bf(a.x); r[1] = (short)f2bf(a.y); r[2] = (short)f2bf(a.z); r[3] = (short)f2bf(a.w);
    r[4] = (short)f2bf(b.x); r[5] = (short)f2bf(b.y); r[6] = (short)f2bf(b.z); r[7] = (short)f2bf(b.w);
    return r;
}
// fragment from global fp32 row-major [row][256], NO clamp (all rows real)
__device__ __forceinline__ bf16x8 xfrag(const float* __restrict__ base, int n, int k0, int lane) {
    const int row = n + (lane & 15);
    const int col = k0 + ((lane >> 4) << 3);
    const float4 a = *(const float4*)(base + (size_t)row * 256 + col);
    const float4 b = *(const float4*)(base + (size_t)row * 256 + col + 4);
    bf16x8 r;
    r[0] = (short)f2bf(a.x); r[1] = (short)f2bf(a.y); r[2] = (short)f2bf(a.z); r[3] = (short)f2bf(a.w);
    r[4] = (short)f2bf(b.x); r[5] = (short)f2bf(b.y); r[6] = (short)f2bf(b.z); r[7] = (short)f2bf(b.w);
    return r;
}
// W fragment straight from global (bf16 ws if available, else fp32 + convert)
__device__ __forceinline__ bf16x8 wfrag(const unsigned short* wbf, const float* wf, int use_ws,
                                        int n, int k0, int lane) {
    const int row = n + (lane & 15);
    const int col = k0 + ((lane >> 4) << 3);
    if (use_ws) {
        return *(const bf16x8*)(wbf + (size_t)row * 256 + col);
    }
    const float4 a = *(const float4*)(wf + (size_t)row * 256 + col);
    const float4 b = *(const float4*)(wf + (size_t)row * 256 + col + 4);
    bf16x8 r;
    r[0] = (short)f2bf(a.x); r[1] = (short)f2bf(a.y); r[2] = (short)f2bf(a.z); r[3] = (short)f2bf(a.w);
    r[4] = (short)f2bf(b.x); r[5] = (short)f2bf(b.y); r[6] = (short)f2bf(b.z); r[7] = (short)f2bf(b.w);
    return r;
}

__global__ void convert_w_kernel(const float* __restrict__ W1, const float* __restrict__ W2,
                                 unsigned short* __restrict__ ws) {
    int i4 = (blockIdx.x * 256 + threadIdx.x) * 4;
    float4 a = *(const float4*)(W1 + i4);
    ushort4 oa; oa.x = f2bf(a.x); oa.y = f2bf(a.y); oa.z = f2bf(a.z); oa.w = f2bf(a.w);
    *(ushort4*)(ws + i4) = oa;
    float4 b = *(const float4*)(W2 + i4);
    ushort4 ob; ob.x = f2bf(b.x); ob.y = f2bf(b.y); ob.z = f2bf(b.z); ob.w = f2bf(b.w);
    *(ushort4*)(ws + 65536 + i4) = ob;
}

// ============================ Kernel 1: attention + LN1 -> X (fp32, into out) ===========
__global__ __launch_bounds__(512, 4) void attn_kernel(
    const float* __restrict__ Q,  const float* __restrict__ K,
    const float* __restrict__ V,  const float* __restrict__ Msk,
    const float* __restrict__ ln1w, const float* __restrict__ ln1b,
    float* __restrict__ out)
{
    __shared__ __align__(16) unsigned char smem[K1_SMEM];
    unsigned short* sVt = (unsigned short*)(smem + K1_OFF_V);
    unsigned short* sS  = (unsigned short*)(smem + K1_OFF_S);
    float*          red = (float*)(smem + K1_OFF_R);   // [u][half][2]

    const int tid  = threadIdx.x;
    const int lane = tid & 63;
    const int wave = tid >> 6;
    const int quad = lane >> 4;
    const int l15  = lane & 15;

    // XCD-chunked swizzle: each XCD owns a contiguous btd chunk of 400
    const int btd = ((blockIdx.x & 7) * 400) + (blockIdx.x >> 3);
    const int b   = btd / (Tt * Dd);
    const int rem = btd % (Tt * Dd);
    const int t   = rem / Dd;
    const int d   = rem % Dd;

    const float* Qb = Q + ((size_t)(b * Tt + t) * Uu) * Ee;
    const float* Kb = K + ((size_t)(b * Dd + d) * Pp) * Ee;
    const float* Vb = V + ((size_t)(b * Dd + d) * Pp) * Ee;
    const float* Mb = Msk + ((size_t)((b * Tt + t) * Dd + d) * Uu) * Pp;
    float*       Xb = out + ((size_t)btd * Uu) * Ee;

    if (wave < 4) {
        // ---- Scores m-tile = wave: Q and K direct from global/L2, softmax in regs ----
        const int mt = wave;
        int arow = mt * 16 + l15; if (arow > 49) arow = 49;
        const float* qrow = Qb + (size_t)arow * Ee + (quad << 3);
        f32x4 acc[4];
        #pragma unroll
        for (int i = 0; i < 4; ++i) acc[i] = (f32x4){0.f, 0.f, 0.f, 0.f};
        #pragma unroll
        for (int k0 = 0; k0 < 256; k0 += 32) {
            float4 qa = *(const float4*)(qrow + k0);
            float4 qb = *(const float4*)(qrow + k0 + 4);
            bf16x8 a;
            a[0] = (short)f2bf(qa.x); a[1] = (short)f2bf(qa.y); a[2] = (short)f2bf(qa.z); a[3] = (short)f2bf(qa.w);
            a[4] = (short)f2bf(qb.x); a[5] = (short)f2bf(qb.y); a[6] = (short)f2bf(qb.z); a[7] = (short)f2bf(qb.w);
            #pragma unroll
            for (int nt = 0; nt < 4; ++nt) {
                bf16x8 bf = gfrag49(Kb, nt << 4, k0, lane);
                acc[nt] = __builtin_amdgcn_mfma_f32_16x16x32_bf16(a, bf, acc[nt], 0, 0, 0);
            }
        }
        // logits: scale 1/16 + mask; p>=50 -> -inf-ish
        float l[4][4];
        #pragma unroll
        for (int nt = 0; nt < 4; ++nt) {
            int p = (nt << 4) + l15;
            #pragma unroll
            for (int r = 0; r < 4; ++r) {
                int u = mt * 16 + (quad << 2) + r;
                float v = acc[nt][r] * 0.0625f;
                if (p < Pp) { if (u < Uu) v += Mb[u * Pp + p]; }
                else v = -1e30f;
                l[nt][r] = v;
            }
        }
        #pragma unroll
        for (int r = 0; r < 4; ++r) {
            float m = fmaxf(fmaxf(l[0][r], l[1][r]), fmaxf(l[2][r], l[3][r]));
            #pragma unroll
            for (int msk = 1; msk < 16; msk <<= 1) m = fmaxf(m, __shfl_xor(m, msk));
            float e0 = __expf(l[0][r] - m), e1 = __expf(l[1][r] - m);
            float e2 = __expf(l[2][r] - m), e3 = __expf(l[3][r] - m);
            float s = e0 + e1 + e2 + e3;
            #pragma unroll
            for (int msk = 1; msk < 16; msk <<= 1) s += __shfl_xor(s, msk);
            float inv = 1.0f / s;
            int u = mt * 16 + (quad << 2) + r;
            sS[u * STS +  0 + l15] = f2bf(e0 * inv);
            sS[u * STS + 16 + l15] = f2bf(e1 * inv);
            sS[u * STS + 32 + l15] = f2bf(e2 * inv);
            sS[u * STS + 48 + l15] = f2bf(e3 * inv);
        }
    } else {
        // ---- Waves 4-7: stage V^T, overlapped with scores ----
        const int lt = tid - 256;
        #pragma unroll 4
        for (int i = lt; i < 12800; i += 256) {
            int p = i >> 8, e = i & 255;
            sVt[e * STV + p] = f2bf(Vb[p * Ee + e]);
        }
        for (int i = lt; i < 3584; i += 256) {   // zero k-pad cols p=50..63
            int p = 50 + (i >> 8), e = i & 255;
            sVt[e * STV + p] = 0;
        }
    }
    __syncthreads();   // B1: sS + sVt ready

    // ---- PV: v_att = S.V (m-tile = w>>1, n-half = w&1) + Q residual + LN1 -> X global ----
    {
        const int mt = wave >> 1;
        const int nh = (wave & 1) << 7;
        f32x4 acc[8];
        #pragma unroll
        for (int i = 0; i < 8; ++i) acc[i] = (f32x4){0.f, 0.f, 0.f, 0.f};
        #pragma unroll
        for (int k0 = 0; k0 < 64; k0 += 32) {
            bf16x8 a = ldfrag(sS, STS, mt << 4, k0, lane);
            #pragma unroll
            for (int nt = 0; nt < 8; ++nt) {
                bf16x8 bf = ldfrag(sVt, STV, nh + (nt << 4), k0, lane);
                acc[nt] = __builtin_amdgcn_mfma_f32_16x16x32_bf16(a, bf, acc[nt], 0, 0, 0);
            }
        }
        float s1[4] = {0.f, 0.f, 0.f, 0.f}, s2[4] = {0.f, 0.f, 0.f, 0.f};
        #pragma unroll
        for (int nt = 0; nt < 8; ++nt) {
            int e = nh + (nt << 4) + l15;
            #pragma unroll
            for (int r = 0; r < 4; ++r) {
                int u = (mt << 4) + (quad << 2) + r;
                float x = 0.f;
                if (u < Uu) x = acc[nt][r] + Qb[(size_t)u * Ee + e];
                acc[nt][r] = x;
                s1[r] += x; s2[r] += x * x;
            }
        }
        #pragma unroll
        for (int msk = 1; msk < 16; msk <<= 1) {
            #pragma unroll
            for (int r = 0; r < 4; ++r) { s1[r] += __shfl_xor(s1[r], msk); s2[r] += __shfl_xor(s2[r], msk); }
        }
        if (l15 == 0) {
            #pragma unroll
            for (int r = 0; r < 4; ++r) {
                int u = (mt << 4) + (quad << 2) + r;
                red[u * 4 + (wave & 1) * 2 + 0] = s1[r];
                red[u * 4 + (wave & 1) * 2 + 1] = s2[r];
            }
        }
        __syncthreads();   // B2: red ready
        #pragma unroll
        for (int r = 0; r < 4; ++r) {
            int u = (mt << 4) + (quad << 2) + r;
            if (u < Uu) {
                float sum = red[u * 4 + 0] + red[u * 4 + 2];
                float sq  = red[u * 4 + 1] + red[u * 4 + 3];
                float mu = sum * (1.0f / 256.0f);
                float var = sq * (1.0f / 256.0f) - mu * mu;
                float rstd = rsqrtf(var + 1e-5f);
                #pragma unroll
                for (int nt = 0; nt < 8; ++nt) {
                    int e = nh + (nt << 4) + l15;
                    Xb[(size_t)u * Ee + e] = (acc[nt][r] - mu) * rstd * ln1w[e] + ln1b[e];
                }
            }
        }
    }
}

// ============================ Kernel 2: FFN + LN2 as flat-M GEMM over X[160000,256] ===========
// Each block owns 128 real rows (1250 x 128 = 160,000 exactly): no guards, no padding.
// 8 waves = 2 row-halves (64 rows) x 4 col-quarters (64 cols); per wave 4x4 16x16 frags.
__global__ __launch_bounds__(512, 4) void ffn_kernel(
    const float* __restrict__ W1, const float* __restrict__ b1,
    const float* __restrict__ W2, const float* __restrict__ b2,
    const float* __restrict__ ln2w, const float* __restrict__ ln2b,
    const unsigned short* __restrict__ wsbf, int use_ws,
    float* __restrict__ out)
{
    __shared__ __align__(16) unsigned char smem[K2_SMEM];
    unsigned short* sH   = (unsigned short*)(smem + K2_OFF_H);
    float*          red2 = (float*)(smem + K2_OFF_R);   // [u][nq][2], u in 0..127

    const int tid  = threadIdx.x;
    const int lane = tid & 63;
    const int wave = tid >> 6;
    const int quad = lane >> 4;
    const int l15  = lane & 15;

    const int mw = wave >> 2;     // 0..1: row-half (rows mw*64 .. +63)
    const int nq = wave & 3;      // 0..3: col-quarter (cols nq*64 .. +63)

    const size_t rowbase = (size_t)blockIdx.x * FFN_BM;
    const float* Xb = out + rowbase * Ee;   // out holds X for these rows
    float*       Ob = out + rowbase * Ee;

    // ---- FFN1: H = relu(X.W1^T + b1); A from global X, W from L2; H -> LDS ----
    {
        f32x4 acc[4][4];
        #pragma unroll
        for (int mi = 0; mi < 4; ++mi)
            #pragma unroll
            for (int nt = 0; nt < 4; ++nt) acc[mi][nt] = (f32x4){0.f, 0.f, 0.f, 0.f};
        float b1v[4];
        #pragma unroll
        for (int nt = 0; nt < 4; ++nt) b1v[nt] = b1[(nq << 6) + (nt << 4) + l15];
        #pragma unroll
        for (int k0 = 0; k0 < 256; k0 += 32) {
            bf16x8 a[4];
            #pragma unroll
            for (int mi = 0; mi < 4; ++mi) a[mi] = xfrag(Xb, (mw << 6) + (mi << 4), k0, lane);
            #pragma unroll
            for (int nt = 0; nt < 4; ++nt) {
                bf16x8 bf = wfrag(wsbf, W1, use_ws, (nq << 6) + (nt << 4), k0, lane);
                #pragma unroll
                for (int mi = 0; mi < 4; ++mi)
                    acc[mi][nt] = __builtin_amdgcn_mfma_f32_16x16x32_bf16(a[mi], bf, acc[mi][nt], 0, 0, 0);
            }
        }
        #pragma unroll
        for (int mi = 0; mi < 4; ++mi)
            #pragma unroll
            for (int nt = 0; nt < 4; ++nt) {
                int j = (nq << 6) + (nt << 4) + l15;
                #pragma unroll
                for (int r = 0; r < 4; ++r) {
                    int u = (mw << 6) + (mi << 4) + (quad << 2) + r;
                    sH[u * STH + j] = f2bf(fmaxf(acc[mi][nt][r] + b1v[nt], 0.f));
                }
            }
    }
    __syncthreads();   // B1: sH ready

    // ---- FFN2: Y = H.W2^T + b2 + X(global); LN2; store over X rows ----
    {
        f32x4 acc[4][4];
        #pragma unroll
        for (int mi = 0; mi < 4; ++mi)
            #pragma unroll
            for (int nt = 0; nt < 4; ++nt) acc[mi][nt] = (f32x4){0.f, 0.f, 0.f, 0.f};
        float b2v[4], w2l[4], b2l[4];
        #pragma unroll
        for (int nt = 0; nt < 4; ++nt) {
            int j = (nq << 6) + (nt << 4) + l15;
            b2v[nt] = b2[j]; w2l[nt] = ln2w[j]; b2l[nt] = ln2b[j];
        }
        #pragma unroll
        for (int k0 = 0; k0 < 256; k0 += 32) {
            bf16x8 a[4];
            #pragma unroll
            for (int mi = 0; mi < 4; ++mi) a[mi] = ldfrag(sH, STH, (mw << 6) + (mi << 4), k0, lane);
            #pragma unroll
            for (int nt = 0; nt < 4; ++nt) {
                bf16x8 bf = wfrag(wsbf + 65536, W2, use_ws, (nq << 6) + (nt << 4), k0, lane);
                #pragma unroll
                for (int mi = 0; mi < 4; ++mi)
                    acc[mi][nt] = __builtin_amdgcn_mfma_f32_16x16x32_bf16(a[mi], bf, acc[mi][nt], 0, 0, 0);
            }
        }
        // y = ffn2 + b2 + residual X; per-mi row partial sums (keeps live regs bounded)
        #pragma unroll
        for (int mi = 0; mi < 4; ++mi) {
            float s1[4] = {0.f, 0.f, 0.f, 0.f}, s2[4] = {0.f, 0.f, 0.f, 0.f};
            #pragma unroll
            for (int nt = 0; nt < 4; ++nt) {
                int j = (nq << 6) + (nt << 4) + l15;
                #pragma unroll
                for (int r = 0; r < 4; ++r) {
                    int u = (mw << 6) + (mi << 4) + (quad << 2) + r;
                    float y = acc[mi][nt][r] + b2v[nt] + Xb[(size_t)u * Ee + j];
                    acc[mi][nt][r] = y;
                    s1[r] += y; s2[r] += y * y;
                }
            }
            #pragma unroll
            for (int msk = 1; msk < 16; msk <<= 1)
                #pragma unroll
                for (int r = 0; r < 4; ++r) {
                    s1[r] += __shfl_xor(s1[r], msk);
                    s2[r] += __shfl_xor(s2[r], msk);
                }
            if (l15 == 0) {
                #pragma unroll
                for (int r = 0; r < 4; ++r) {
                    int u = (mw << 6) + (mi << 4) + (quad << 2) + r;
                    red2[u * 8 + nq * 2 + 0] = s1[r];
                    red2[u * 8 + nq * 2 + 1] = s2[r];
                }
            }
        }
        __syncthreads();   // B2: red2 ready
        #pragma unroll
        for (int mi = 0; mi < 4; ++mi)
            #pragma unroll
            for (int r = 0; r < 4; ++r) {
                int u = (mw << 6) + (mi << 4) + (quad << 2) + r;
                float sum = red2[u * 8 + 0] + red2[u * 8 + 2] + red2[u * 8 + 4] + red2[u * 8 + 6];
                float sq  = red2[u * 8 + 1] + red2[u * 8 + 3] + red2[u * 8 + 5] + red2[u * 8 + 7];
                float mu = sum * (1.0f / 256.0f);
                float var = sq * (1.0f / 256.0f) - mu * mu;
                float rstd = rsqrtf(var + 1e-5f);
                #pragma unroll
                for (int nt = 0; nt < 4; ++nt) {
                    int j = (nq << 6) + (nt << 4) + l15;
                    Ob[(size_t)u * Ee + j] = (acc[mi][nt][r] - mu) * rstd * w2l[nt] + b2l[nt];
                }
            }
    }
}

extern "C" void kernel_launch(void* const* d_in, const int* in_sizes, int n_in,
                              void* d_out, int out_size, void* d_ws, size_t ws_size,
                              hipStream_t stream) {
    const float* Q    = (const float*)d_in[0];
    const float* K    = (const float*)d_in[1];
    const float* V    = (const float*)d_in[2];
    const float* M    = (const float*)d_in[3];
    const float* W1   = (const float*)d_in[4];
    const float* b1   = (const float*)d_in[5];
    const float* W2   = (const float*)d_in[6];
    const float* b2   = (const float*)d_in[7];
    const float* ln1w = (const float*)d_in[8];
    const float* ln1b = (const float*)d_in[9];
    const float* ln2w = (const float*)d_in[10];
    const float* ln2b = (const float*)d_in[11];
    float* out = (float*)d_out;

    int use_ws = (ws_size >= 262144) ? 1 : 0;
    const unsigned short* wsbf = (const unsigned short*)d_ws;
    if (use_ws) {
        convert_w_kernel<<<64, 256, 0, stream>>>(W1, W2, (unsigned short*)d_ws);
    }
    attn_kernel<<<Bsz * Tt * Dd, 512, 0, stream>>>(Q, K, V, M, ln1w, ln1b, out);
    ffn_kernel<<<(Bsz * Tt * Dd * Uu) / FFN_BM, 512, 0, stream>>>(W1, b1, W2, b2, ln2w, ln2b,
                                                                  wsbf, use_ws, out);
}

// Round 6
// 561.614 us; speedup vs baseline: 1.2158x; 1.2158x over previous
//
#include <hip/hip_runtime.h>
#include <math.h>

#define Bsz 32
#define Tt  10
#define Dd  10
#define Uu  50
#define Pp  50
#define Ee  256

typedef __attribute__((ext_vector_type(8))) short bf16x8;   // MFMA A/B frag
typedef __attribute__((ext_vector_type(4))) float f32x4;    // MFMA C/D frag

#define STH 264   // sH row stride (halfwords)
#define STV 72    // sVt row stride
#define STS 72    // sS row stride

// kernel1 (attention) LDS: sVt 256x72x2=36864 | sS 64x72x2=9216 | red 1024
#define K1_OFF_V 0
#define K1_OFF_S 36864
#define K1_OFF_R 46080
#define K1_SMEM  47104   // 3 blocks/CU

// kernel2 (FFN) LDS: sH 128x264x2=67584 | red2 4096
#define K2_OFF_H 0
#define K2_OFF_R 67584
#define K2_SMEM  71680   // 2 blocks/CU
#define FFN_BM 128

// bf16 workspace layout (ushort element offsets)
#define WS_Q   0
#define WS_K   4096000
#define WS_V   8192000
#define WS_W1  12288000
#define WS_W2  12353536
#define WS_X   12419072
#define WS_NEED_BYTES 106758144ull   // (WS_X + 160000*256) * 2

__device__ __forceinline__ unsigned short f2bf(float f) {      // RNE fp32->bf16
    unsigned u = __builtin_bit_cast(unsigned, f);
    u += 0x7fffu + ((u >> 16) & 1u);
    return (unsigned short)(u >> 16);
}
__device__ __forceinline__ float bf2f(unsigned short h) {
    unsigned u = ((unsigned)h) << 16;
    return __builtin_bit_cast(float, u);
}
// A/B fragment from LDS: lane q*16+l15 -> row r0+l15, cols c0+q*8..+7 (b128)
__device__ __forceinline__ bf16x8 ldfrag(const unsigned short* p, int stride, int r0, int c0, int lane) {
    return *(const bf16x8*)(p + (size_t)(r0 + (lane & 15)) * stride + c0 + ((lane >> 4) << 3));
}
// fragment from global bf16 row-major [row][256]; optional clamp at 49
__device__ __forceinline__ bf16x8 bffrag(const unsigned short* __restrict__ base, int n, int k0, int lane) {
    const int row = n + (lane & 15);
    return *(const bf16x8*)(base + (size_t)row * 256 + k0 + ((lane >> 4) << 3));
}
__device__ __forceinline__ bf16x8 bffrag49(const unsigned short* __restrict__ base, int n, int k0, int lane) {
    int row = n + (lane & 15);
    row = row > 49 ? 49 : row;
    return *(const bf16x8*)(base + (size_t)row * 256 + k0 + ((lane >> 4) << 3));
}
// ---------- legacy fp32 helpers (fallback path, identical to round-5) ----------
__device__ __forceinline__ bf16x8 gfrag49(const float* __restrict__ base, int n, int k0, int lane) {
    int row = n + (lane & 15);
    row = row > 49 ? 49 : row;
    const int col = k0 + ((lane >> 4) << 3);
    const float4 a = *(const float4*)(base + (size_t)row * 256 + col);
    const float4 b = *(const float4*)(base + (size_t)row * 256 + col + 4);
    bf16x8 r;
    r[0] = (short)f2bf(a.x); r[1] = (short)f2bf(a.y); r[2] = (short)f2bf(a.z); r[3] = (short)f2bf(a.w);
    r[4] = (short)f2bf(b.x); r[5] = (short)f2bf(b.y); r[6] = (short)f2bf(b.z); r[7] = (short)f2bf(b.w);
    return r;
}
__device__ __forceinline__ bf16x8 xfrag(const float* __restrict__ base, int n, int k0, int lane) {
    const int row = n + (lane & 15);
    const int col = k0 + ((lane >> 4) << 3);
    const float4 a = *(const float4*)(base + (size_t)row * 256 + col);
    const float4 b = *(const float4*)(base + (size_t)row * 256 + col + 4);
    bf16x8 r;
    r[0] = (short)f2bf(a.x); r[1] = (short)f2bf(a.y); r[2] = (short)f2bf(a.z); r[3] = (short)f2bf(a.w);
    r[4] = (short)f2bf(b.x); r[5] = (short)f2bf(b.y); r[6] = (short)f2bf(b.z); r[7] = (short)f2bf(b.w);
    return r;
}
__device__ __forceinline__ bf16x8 wfrag(const unsigned short* wbf, const float* wf, int use_ws,
                                        int n, int k0, int lane) {
    const int row = n + (lane & 15);
    const int col = k0 + ((lane >> 4) << 3);
    if (use_ws) {
        return *(const bf16x8*)(wbf + (size_t)row * 256 + col);
    }
    const float4 a = *(const float4*)(wf + (size_t)row * 256 + col);
    const float4 b = *(const float4*)(wf + (size_t)row * 256 + col + 4);
    bf16x8 r;
    r[0] = (short)f2bf(a.x); r[1] = (short)f2bf(a.y); r[2] = (short)f2bf(a.z); r[3] = (short)f2bf(a.w);
    r[4] = (short)f2bf(b.x); r[5] = (short)f2bf(b.y); r[6] = (short)f2bf(b.z); r[7] = (short)f2bf(b.w);
    return r;
}

// ===================== bf16 pre-convert: Q,K,V,W1,W2 -> ws ======================
__global__ __launch_bounds__(256) void cvt_kernel(
    const float* __restrict__ Q, const float* __restrict__ K, const float* __restrict__ V,
    const float* __restrict__ W1, const float* __restrict__ W2, unsigned short* __restrict__ ws)
{
    const int blk = blockIdx.x, t = threadIdx.x;
    const float* src; unsigned short* dst; int f4base;
    if (blk < 1000)      { src = Q;  dst = ws + WS_Q;  f4base = blk * 1024; }
    else if (blk < 2000) { src = K;  dst = ws + WS_K;  f4base = (blk - 1000) * 1024; }
    else if (blk < 3000) { src = V;  dst = ws + WS_V;  f4base = (blk - 2000) * 1024; }
    else if (blk < 3016) { src = W1; dst = ws + WS_W1; f4base = (blk - 3000) * 1024; }
    else                 { src = W2; dst = ws + WS_W2; f4base = (blk - 3016) * 1024; }
    #pragma unroll
    for (int j = 0; j < 4; ++j) {
        int i4 = f4base + t + j * 256;
        float4 v = *(const float4*)(src + (size_t)i4 * 4);
        ushort4 o; o.x = f2bf(v.x); o.y = f2bf(v.y); o.z = f2bf(v.z); o.w = f2bf(v.w);
        *(ushort4*)(dst + (size_t)i4 * 4) = o;
    }
}

__global__ void convert_w_kernel(const float* __restrict__ W1, const float* __restrict__ W2,
                                 unsigned short* __restrict__ ws) {
    int i4 = (blockIdx.x * 256 + threadIdx.x) * 4;
    float4 a = *(const float4*)(W1 + i4);
    ushort4 oa; oa.x = f2bf(a.x); oa.y = f2bf(a.y); oa.z = f2bf(a.z); oa.w = f2bf(a.w);
    *(ushort4*)(ws + i4) = oa;
    float4 b = *(const float4*)(W2 + i4);
    ushort4 ob; ob.x = f2bf(b.x); ob.y = f2bf(b.y); ob.z = f2bf(b.z); ob.w = f2bf(b.w);
    *(ushort4*)(ws + 65536 + i4) = ob;
}

// ===================== Kernel 1 (fast): attention + LN1 -> X bf16 in ws =====================
__global__ __launch_bounds__(512, 4) void attn_bf_kernel(
    const float* __restrict__ Q, const float* __restrict__ Msk,
    const float* __restrict__ ln1w, const float* __restrict__ ln1b,
    unsigned short* __restrict__ ws)
{
    __shared__ __align__(16) unsigned char smem[K1_SMEM];
    unsigned short* sVt = (unsigned short*)(smem + K1_OFF_V);
    unsigned short* sS  = (unsigned short*)(smem + K1_OFF_S);
    float*          red = (float*)(smem + K1_OFF_R);

    const int tid  = threadIdx.x;
    const int lane = tid & 63;
    const int wave = tid >> 6;
    const int quad = lane >> 4;
    const int l15  = lane & 15;

    const int btd = ((blockIdx.x & 7) * 400) + (blockIdx.x >> 3);
    const int b   = btd / (Tt * Dd);
    const int rem = btd % (Tt * Dd);
    const int t   = rem / Dd;
    const int d   = rem % Dd;

    const float* Qb = Q + ((size_t)(b * Tt + t) * Uu) * Ee;
    const unsigned short* Qbf = ws + WS_Q + (size_t)(b * Tt + t) * Uu * Ee;
    const unsigned short* Kbf = ws + WS_K + (size_t)(b * Dd + d) * Pp * Ee;
    const unsigned short* Vbf = ws + WS_V + (size_t)(b * Dd + d) * Pp * Ee;
    const float* Mb = Msk + ((size_t)((b * Tt + t) * Dd + d) * Uu) * Pp;
    unsigned short* Xbf = ws + WS_X + (size_t)btd * Uu * Ee;

    if (wave < 4) {
        // ---- Scores: Q and K bf16 fragments straight from ws (one 16B load each) ----
        const int mt = wave;
        int arow = mt * 16 + l15; if (arow > 49) arow = 49;
        const unsigned short* qrow = Qbf + (size_t)arow * Ee + (quad << 3);
        f32x4 acc[4];
        #pragma unroll
        for (int i = 0; i < 4; ++i) acc[i] = (f32x4){0.f, 0.f, 0.f, 0.f};
        #pragma unroll
        for (int k0 = 0; k0 < 256; k0 += 32) {
            bf16x8 a = *(const bf16x8*)(qrow + k0);
            #pragma unroll
            for (int nt = 0; nt < 4; ++nt) {
                bf16x8 bf = bffrag49(Kbf, nt << 4, k0, lane);
                acc[nt] = __builtin_amdgcn_mfma_f32_16x16x32_bf16(a, bf, acc[nt], 0, 0, 0);
            }
        }
        float l[4][4];
        #pragma unroll
        for (int nt = 0; nt < 4; ++nt) {
            int p = (nt << 4) + l15;
            #pragma unroll
            for (int r = 0; r < 4; ++r) {
                int u = mt * 16 + (quad << 2) + r;
                float v = acc[nt][r] * 0.0625f;
                if (p < Pp) { if (u < Uu) v += Mb[u * Pp + p]; }
                else v = -1e30f;
                l[nt][r] = v;
            }
        }
        #pragma unroll
        for (int r = 0; r < 4; ++r) {
            float m = fmaxf(fmaxf(l[0][r], l[1][r]), fmaxf(l[2][r], l[3][r]));
            #pragma unroll
            for (int msk = 1; msk < 16; msk <<= 1) m = fmaxf(m, __shfl_xor(m, msk));
            float e0 = __expf(l[0][r] - m), e1 = __expf(l[1][r] - m);
            float e2 = __expf(l[2][r] - m), e3 = __expf(l[3][r] - m);
            float s = e0 + e1 + e2 + e3;
            #pragma unroll
            for (int msk = 1; msk < 16; msk <<= 1) s += __shfl_xor(s, msk);
            float inv = 1.0f / s;
            int u = mt * 16 + (quad << 2) + r;
            sS[u * STS +  0 + l15] = f2bf(e0 * inv);
            sS[u * STS + 16 + l15] = f2bf(e1 * inv);
            sS[u * STS + 32 + l15] = f2bf(e2 * inv);
            sS[u * STS + 48 + l15] = f2bf(e3 * inv);
        }
    } else {
        // ---- Waves 4-7: stage V^T from bf16 V (16B loads, 8 scalar LDS writes) ----
        const int lt = tid - 256;
        for (int i = lt; i < 1600; i += 256) {        // 50 p-rows x 32 e-chunks
            int p = i >> 5, e8 = (i & 31) << 3;
            bf16x8 v8 = *(const bf16x8*)(Vbf + (size_t)p * Ee + e8);
            #pragma unroll
            for (int j = 0; j < 8; ++j) sVt[(e8 + j) * STV + p] = (unsigned short)v8[j];
        }
        for (int i = lt; i < 3584; i += 256) {        // zero k-pad cols p=50..63
            int p = 50 + (i >> 8), e = i & 255;
            sVt[e * STV + p] = 0;
        }
    }
    __syncthreads();   // B1: sS + sVt ready

    // ---- PV + Q residual + LN1 -> X bf16 ----
    {
        const int mt = wave >> 1;
        const int nh = (wave & 1) << 7;
        f32x4 acc[8];
        #pragma unroll
        for (int i = 0; i < 8; ++i) acc[i] = (f32x4){0.f, 0.f, 0.f, 0.f};
        #pragma unroll
        for (int k0 = 0; k0 < 64; k0 += 32) {
            bf16x8 a = ldfrag(sS, STS, mt << 4, k0, lane);
            #pragma unroll
            for (int nt = 0; nt < 8; ++nt) {
                bf16x8 bf = ldfrag(sVt, STV, nh + (nt << 4), k0, lane);
                acc[nt] = __builtin_amdgcn_mfma_f32_16x16x32_bf16(a, bf, acc[nt], 0, 0, 0);
            }
        }
        float s1[4] = {0.f, 0.f, 0.f, 0.f}, s2[4] = {0.f, 0.f, 0.f, 0.f};
        #pragma unroll
        for (int nt = 0; nt < 8; ++nt) {
            int e = nh + (nt << 4) + l15;
            #pragma unroll
            for (int r = 0; r < 4; ++r) {
                int u = (mt << 4) + (quad << 2) + r;
                float x = 0.f;
                if (u < Uu) x = acc[nt][r] + Qb[(size_t)u * Ee + e];
                acc[nt][r] = x;
                s1[r] += x; s2[r] += x * x;
            }
        }
        #pragma unroll
        for (int msk = 1; msk < 16; msk <<= 1) {
            #pragma unroll
            for (int r = 0; r < 4; ++r) { s1[r] += __shfl_xor(s1[r], msk); s2[r] += __shfl_xor(s2[r], msk); }
        }
        if (l15 == 0) {
            #pragma unroll
            for (int r = 0; r < 4; ++r) {
                int u = (mt << 4) + (quad << 2) + r;
                red[u * 4 + (wave & 1) * 2 + 0] = s1[r];
                red[u * 4 + (wave & 1) * 2 + 1] = s2[r];
            }
        }
        __syncthreads();   // B2
        #pragma unroll
        for (int r = 0; r < 4; ++r) {
            int u = (mt << 4) + (quad << 2) + r;
            if (u < Uu) {
                float sum = red[u * 4 + 0] + red[u * 4 + 2];
                float sq  = red[u * 4 + 1] + red[u * 4 + 3];
                float mu = sum * (1.0f / 256.0f);
                float var = sq * (1.0f / 256.0f) - mu * mu;
                float rstd = rsqrtf(var + 1e-5f);
                #pragma unroll
                for (int nt = 0; nt < 8; ++nt) {
                    int e = nh + (nt << 4) + l15;
                    Xbf[(size_t)u * Ee + e] = f2bf((acc[nt][r] - mu) * rstd * ln1w[e] + ln1b[e]);
                }
            }
        }
    }
}

// ===================== Kernel 2 (fast): FFN + LN2, X bf16 from ws -> out =====================
__global__ __launch_bounds__(512, 4) void ffn_bf_kernel(
    const float* __restrict__ b1, const float* __restrict__ b2,
    const float* __restrict__ ln2w, const float* __restrict__ ln2b,
    const unsigned short* __restrict__ ws, float* __restrict__ out)
{
    __shared__ __align__(16) unsigned char smem[K2_SMEM];
    unsigned short* sH   = (unsigned short*)(smem + K2_OFF_H);
    float*          red2 = (float*)(smem + K2_OFF_R);

    const int tid  = threadIdx.x;
    const int lane = tid & 63;
    const int wave = tid >> 6;
    const int quad = lane >> 4;
    const int l15  = lane & 15;

    const int mw = wave >> 2;
    const int nq = wave & 3;

    const size_t rowbase = (size_t)blockIdx.x * FFN_BM;
    const unsigned short* Xbf = ws + WS_X + rowbase * Ee;
    const unsigned short* W1bf = ws + WS_W1;
    const unsigned short* W2bf = ws + WS_W2;
    float* Ob = out + rowbase * Ee;

    // ---- FFN1: H = relu(X.W1^T + b1); A and W both bf16 single-load frags ----
    {
        f32x4 acc[4][4];
        #pragma unroll
        for (int mi = 0; mi < 4; ++mi)
            #pragma unroll
            for (int nt = 0; nt < 4; ++nt) acc[mi][nt] = (f32x4){0.f, 0.f, 0.f, 0.f};
        float b1v[4];
        #pragma unroll
        for (int nt = 0; nt < 4; ++nt) b1v[nt] = b1[(nq << 6) + (nt << 4) + l15];
        #pragma unroll
        for (int k0 = 0; k0 < 256; k0 += 32) {
            bf16x8 a[4];
            #pragma unroll
            for (int mi = 0; mi < 4; ++mi) a[mi] = bffrag(Xbf, (mw << 6) + (mi << 4), k0, lane);
            #pragma unroll
            for (int nt = 0; nt < 4; ++nt) {
                bf16x8 bf = bffrag(W1bf, (nq << 6) + (nt << 4), k0, lane);
                #pragma unroll
                for (int mi = 0; mi < 4; ++mi)
                    acc[mi][nt] = __builtin_amdgcn_mfma_f32_16x16x32_bf16(a[mi], bf, acc[mi][nt], 0, 0, 0);
            }
        }
        #pragma unroll
        for (int mi = 0; mi < 4; ++mi)
            #pragma unroll
            for (int nt = 0; nt < 4; ++nt) {
                int j = (nq << 6) + (nt << 4) + l15;
                #pragma unroll
                for (int r = 0; r < 4; ++r) {
                    int u = (mw << 6) + (mi << 4) + (quad << 2) + r;
                    sH[u * STH + j] = f2bf(fmaxf(acc[mi][nt][r] + b1v[nt], 0.f));
                }
            }
    }
    __syncthreads();   // B1

    // ---- FFN2: Y = H.W2^T + b2 + X(bf16 ws); LN2; store ----
    {
        f32x4 acc[4][4];
        #pragma unroll
        for (int mi = 0; mi < 4; ++mi)
            #pragma unroll
            for (int nt = 0; nt < 4; ++nt) acc[mi][nt] = (f32x4){0.f, 0.f, 0.f, 0.f};
        float b2v[4], w2l[4], b2l[4];
        #pragma unroll
        for (int nt = 0; nt < 4; ++nt) {
            int j = (nq << 6) + (nt << 4) + l15;
            b2v[nt] = b2[j]; w2l[nt] = ln2w[j]; b2l[nt] = ln2b[j];
        }
        #pragma unroll
        for (int k0 = 0; k0 < 256; k0 += 32) {
            bf16x8 a[4];
            #pragma unroll
            for (int mi = 0; mi < 4; ++mi) a[mi] = ldfrag(sH, STH, (mw << 6) + (mi << 4), k0, lane);
            #pragma unroll
            for (int nt = 0; nt < 4; ++nt) {
                bf16x8 bf = bffrag(W2bf, (nq << 6) + (nt << 4), k0, lane);
                #pragma unroll
                for (int mi = 0; mi < 4; ++mi)
                    acc[mi][nt] = __builtin_amdgcn_mfma_f32_16x16x32_bf16(a[mi], bf, acc[mi][nt], 0, 0, 0);
            }
        }
        #pragma unroll
        for (int mi = 0; mi < 4; ++mi) {
            float s1[4] = {0.f, 0.f, 0.f, 0.f}, s2[4] = {0.f, 0.f, 0.f, 0.f};
            #pragma unroll
            for (int nt = 0; nt < 4; ++nt) {
                int j = (nq << 6) + (nt << 4) + l15;
                #pragma unroll
                for (int r = 0; r < 4; ++r) {
                    int u = (mw << 6) + (mi << 4) + (quad << 2) + r;
                    float y = acc[mi][nt][r] + b2v[nt] + bf2f(Xbf[(size_t)u * Ee + j]);
                    acc[mi][nt][r] = y;
                    s1[r] += y; s2[r] += y * y;
                }
            }
            #pragma unroll
            for (int msk = 1; msk < 16; msk <<= 1)
                #pragma unroll
                for (int r = 0; r < 4; ++r) {
                    s1[r] += __shfl_xor(s1[r], msk);
                    s2[r] += __shfl_xor(s2[r], msk);
                }
            if (l15 == 0) {
                #pragma unroll
                for (int r = 0; r < 4; ++r) {
                    int u = (mw << 6) + (mi << 4) + (quad << 2) + r;
                    red2[u * 8 + nq * 2 + 0] = s1[r];
                    red2[u * 8 + nq * 2 + 1] = s2[r];
                }
            }
        }
        __syncthreads();   // B2
        #pragma unroll
        for (int mi = 0; mi < 4; ++mi)
            #pragma unroll
            for (int r = 0; r < 4; ++r) {
                int u = (mw << 6) + (mi << 4) + (quad << 2) + r;
                float sum = red2[u * 8 + 0] + red2[u * 8 + 2] + red2[u * 8 + 4] + red2[u * 8 + 6];
                float sq  = red2[u * 8 + 1] + red2[u * 8 + 3] + red2[u * 8 + 5] + red2[u * 8 + 7];
                float mu = sum * (1.0f / 256.0f);
                float var = sq * (1.0f / 256.0f) - mu * mu;
                float rstd = rsqrtf(var + 1e-5f);
                #pragma unroll
                for (int nt = 0; nt < 4; ++nt) {
                    int j = (nq << 6) + (nt << 4) + l15;
                    Ob[(size_t)u * Ee + j] = (acc[mi][nt][r] - mu) * rstd * w2l[nt] + b2l[nt];
                }
            }
    }
}

// ===================== Fallback kernels (round-5, verified) =====================
__global__ __launch_bounds__(512, 4) void attn_kernel(
    const float* __restrict__ Q,  const float* __restrict__ K,
    const float* __restrict__ V,  const float* __restrict__ Msk,
    const float* __restrict__ ln1w, const float* __restrict__ ln1b,
    float* __restrict__ out)
{
    __shared__ __align__(16) unsigned char smem[K1_SMEM];
    unsigned short* sVt = (unsigned short*)(smem + K1_OFF_V);
    unsigned short* sS  = (unsigned short*)(smem + K1_OFF_S);
    float*          red = (float*)(smem + K1_OFF_R);

    const int tid  = threadIdx.x;
    const int lane = tid & 63;
    const int wave = tid >> 6;
    const int quad = lane >> 4;
    const int l15  = lane & 15;

    const int btd = ((blockIdx.x & 7) * 400) + (blockIdx.x >> 3);
    const int b   = btd / (Tt * Dd);
    const int rem = btd % (Tt * Dd);
    const int t   = rem / Dd;
    const int d   = rem % Dd;

    const float* Qb = Q + ((size_t)(b * Tt + t) * Uu) * Ee;
    const float* Kb = K + ((size_t)(b * Dd + d) * Pp) * Ee;
    const float* Vb = V + ((size_t)(b * Dd + d) * Pp) * Ee;
    const float* Mb = Msk + ((size_t)((b * Tt + t) * Dd + d) * Uu) * Pp;
    float*       Xb = out + ((size_t)btd * Uu) * Ee;

    if (wave < 4) {
        const int mt = wave;
        int arow = mt * 16 + l15; if (arow > 49) arow = 49;
        const float* qrow = Qb + (size_t)arow * Ee + (quad << 3);
        f32x4 acc[4];
        #pragma unroll
        for (int i = 0; i < 4; ++i) acc[i] = (f32x4){0.f, 0.f, 0.f, 0.f};
        #pragma unroll
        for (int k0 = 0; k0 < 256; k0 += 32) {
            float4 qa = *(const float4*)(qrow + k0);
            float4 qb = *(const float4*)(qrow + k0 + 4);
            bf16x8 a;
            a[0] = (short)f2bf(qa.x); a[1] = (short)f2bf(qa.y); a[2] = (short)f2bf(qa.z); a[3] = (short)f2bf(qa.w);
            a[4] = (short)f2bf(qb.x); a[5] = (short)f2bf(qb.y); a[6] = (short)f2bf(qb.z); a[7] = (short)f2bf(qb.w);
            #pragma unroll
            for (int nt = 0; nt < 4; ++nt) {
                bf16x8 bf = gfrag49(Kb, nt << 4, k0, lane);
                acc[nt] = __builtin_amdgcn_mfma_f32_16x16x32_bf16(a, bf, acc[nt], 0, 0, 0);
            }
        }
        float l[4][4];
        #pragma unroll
        for (int nt = 0; nt < 4; ++nt) {
            int p = (nt << 4) + l15;
            #pragma unroll
            for (int r = 0; r < 4; ++r) {
                int u = mt * 16 + (quad << 2) + r;
                float v = acc[nt][r] * 0.0625f;
                if (p < Pp) { if (u < Uu) v += Mb[u * Pp + p]; }
                else v = -1e30f;
                l[nt][r] = v;
            }
        }
        #pragma unroll
        for (int r = 0; r < 4; ++r) {
            float m = fmaxf(fmaxf(l[0][r], l[1][r]), fmaxf(l[2][r], l[3][r]));
            #pragma unroll
            for (int msk = 1; msk < 16; msk <<= 1) m = fmaxf(m, __shfl_xor(m, msk));
            float e0 = __expf(l[0][r] - m), e1 = __expf(l[1][r] - m);
            float e2 = __expf(l[2][r] - m), e3 = __expf(l[3][r] - m);
            float s = e0 + e1 + e2 + e3;
            #pragma unroll
            for (int msk = 1; msk < 16; msk <<= 1) s += __shfl_xor(s, msk);
            float inv = 1.0f / s;
            int u = mt * 16 + (quad << 2) + r;
            sS[u * STS +  0 + l15] = f2bf(e0 * inv);
            sS[u * STS + 16 + l15] = f2bf(e1 * inv);
            sS[u * STS + 32 + l15] = f2bf(e2 * inv);
            sS[u * STS + 48 + l15] = f2bf(e3 * inv);
        }
    } else {
        const int lt = tid - 256;
        #pragma unroll 4
        for (int i = lt; i < 12800; i += 256) {
            int p = i >> 8, e = i & 255;
            sVt[e * STV + p] = f2bf(Vb[p * Ee + e]);
        }
        for (int i = lt; i < 3584; i += 256) {
            int p = 50 + (i >> 8), e = i & 255;
            sVt[e * STV + p] = 0;
        }
    }
    __syncthreads();

    {
        const int mt = wave >> 1;
        const int nh = (wave & 1) << 7;
        f32x4 acc[8];
        #pragma unroll
        for (int i = 0; i < 8; ++i) acc[i] = (f32x4){0.f, 0.f, 0.f, 0.f};
        #pragma unroll
        for (int k0 = 0; k0 < 64; k0 += 32) {
            bf16x8 a = ldfrag(sS, STS, mt << 4, k0, lane);
            #pragma unroll
            for (int nt = 0; nt < 8; ++nt) {
                bf16x8 bf = ldfrag(sVt, STV, nh + (nt << 4), k0, lane);
                acc[nt] = __builtin_amdgcn_mfma_f32_16x16x32_bf16(a, bf, acc[nt], 0, 0, 0);
            }
        }
        float s1[4] = {0.f, 0.f, 0.f, 0.f}, s2[4] = {0.f, 0.f, 0.f, 0.f};
        #pragma unroll
        for (int nt = 0; nt < 8; ++nt) {
            int e = nh + (nt << 4) + l15;
            #pragma unroll
            for (int r = 0; r < 4; ++r) {
                int u = (mt << 4) + (quad << 2) + r;
                float x = 0.f;
                if (u < Uu) x = acc[nt][r] + Qb[(size_t)u * Ee + e];
                acc[nt][r] = x;
                s1[r] += x; s2[r] += x * x;
            }
        }
        #pragma unroll
        for (int msk = 1; msk < 16; msk <<= 1) {
            #pragma unroll
            for (int r = 0; r < 4; ++r) { s1[r] += __shfl_xor(s1[r], msk); s2[r] += __shfl_xor(s2[r], msk); }
        }
        if (l15 == 0) {
            #pragma unroll
            for (int r = 0; r < 4; ++r) {
                int u = (mt << 4) + (quad << 2) + r;
                red[u * 4 + (wave & 1) * 2 + 0] = s1[r];
                red[u * 4 + (wave & 1) * 2 + 1] = s2[r];
            }
        }
        __syncthreads();
        #pragma unroll
        for (int r = 0; r < 4; ++r) {
            int u = (mt << 4) + (quad << 2) + r;
            if (u < Uu) {
                float sum = red[u * 4 + 0] + red[u * 4 + 2];
                float sq  = red[u * 4 + 1] + red[u * 4 + 3];
                float mu = sum * (1.0f / 256.0f);
                float var = sq * (1.0f / 256.0f) - mu * mu;
                float rstd = rsqrtf(var + 1e-5f);
                #pragma unroll
                for (int nt = 0; nt < 8; ++nt) {
                    int e = nh + (nt << 4) + l15;
                    Xb[(size_t)u * Ee + e] = (acc[nt][r] - mu) * rstd * ln1w[e] + ln1b[e];
                }
            }
        }
    }
}

__global__ __launch_bounds__(512, 4) void ffn_kernel(
    const float* __restrict__ W1, const float* __restrict__ b1,
    const float* __restrict__ W2, const float* __restrict__ b2,
    const float* __restrict__ ln2w, const float* __restrict__ ln2b,
    const unsigned short* __restrict__ wsbf, int use_ws,
    float* __restrict__ out)
{
    __shared__ __align__(16) unsigned char smem[K2_SMEM];
    unsigned short* sH   = (unsigned short*)(smem + K2_OFF_H);
    float*          red2 = (float*)(smem + K2_OFF_R);

    const int tid  = threadIdx.x;
    const int lane = tid & 63;
    const int wave = tid >> 6;
    const int quad = lane >> 4;
    const int l15  = lane & 15;

    const int mw = wave >> 2;
    const int nq = wave & 3;

    const size_t rowbase = (size_t)blockIdx.x * FFN_BM;
    const float* Xb = out + rowbase * Ee;
    float*       Ob = out + rowbase * Ee;

    {
        f32x4 acc[4][4];
        #pragma unroll
        for (int mi = 0; mi < 4; ++mi)
            #pragma unroll
            for (int nt = 0; nt < 4; ++nt) acc[mi][nt] = (f32x4){0.f, 0.f, 0.f, 0.f};
        float b1v[4];
        #pragma unroll
        for (int nt = 0; nt < 4; ++nt) b1v[nt] = b1[(nq << 6) + (nt << 4) + l15];
        #pragma unroll
        for (int k0 = 0; k0 < 256; k0 += 32) {
            bf16x8 a[4];
            #pragma unroll
            for (int mi = 0; mi < 4; ++mi) a[mi] = xfrag(Xb, (mw << 6) + (mi << 4), k0, lane);
            #pragma unroll
            for (int nt = 0; nt < 4; ++nt) {
                bf16x8 bf = wfrag(wsbf, W1, use_ws, (nq << 6) + (nt << 4), k0, lane);
                #pragma unroll
                for (int mi = 0; mi < 4; ++mi)
                    acc[mi][nt] = __builtin_amdgcn_mfma_f32_16x16x32_bf16(a[mi], bf, acc[mi][nt], 0, 0, 0);
            }
        }
        #pragma unroll
        for (int mi = 0; mi < 4; ++mi)
            #pragma unroll
            for (int nt = 0; nt < 4; ++nt) {
                int j = (nq << 6) + (nt << 4) + l15;
                #pragma unroll
                for (int r = 0; r < 4; ++r) {
                    int u = (mw << 6) + (mi << 4) + (quad << 2) + r;
                    sH[u * STH + j] = f2bf(fmaxf(acc[mi][nt][r] + b1v[nt], 0.f));
                }
            }
    }
    __syncthreads();

    {
        f32x4 acc[4][4];
        #pragma unroll
        for (int mi = 0; mi < 4; ++mi)
            #pragma unroll
            for (int nt = 0; nt < 4; ++nt) acc[mi][nt] = (f32x4){0.f, 0.f, 0.f, 0.f};
        float b2v[4], w2l[4], b2l[4];
        #pragma unroll
        for (int nt = 0; nt < 4; ++nt) {
            int j = (nq << 6) + (nt << 4) + l15;
            b2v[nt] = b2[j]; w2l[nt] = ln2w[j]; b2l[nt] = ln2b[j];
        }
        #pragma unroll
        for (int k0 = 0; k0 < 256; k0 += 32) {
            bf16x8 a[4];
            #pragma unroll
            for (int mi = 0; mi < 4; ++mi) a[mi] = ldfrag(sH, STH, (mw << 6) + (mi << 4), k0, lane);
            #pragma unroll
            for (int nt = 0; nt < 4; ++nt) {
                bf16x8 bf = wfrag(wsbf + 65536, W2, use_ws, (nq << 6) + (nt << 4), k0, lane);
                #pragma unroll
                for (int mi = 0; mi < 4; ++mi)
                    acc[mi][nt] = __builtin_amdgcn_mfma_f32_16x16x32_bf16(a[mi], bf, acc[mi][nt], 0, 0, 0);
            }
        }
        #pragma unroll
        for (int mi = 0; mi < 4; ++mi) {
            float s1[4] = {0.f, 0.f, 0.f, 0.f}, s2[4] = {0.f, 0.f, 0.f, 0.f};
            #pragma unroll
            for (int nt = 0; nt < 4; ++nt) {
                int j = (nq << 6) + (nt << 4) + l15;
                #pragma unroll
                for (int r = 0; r < 4; ++r) {
                    int u = (mw << 6) + (mi << 4) + (quad << 2) + r;
                    float y = acc[mi][nt][r] + b2v[nt] + Xb[(size_t)u * Ee + j];
                    acc[mi][nt][r] = y;
                    s1[r] += y; s2[r] += y * y;
                }
            }
            #pragma unroll
            for (int msk = 1; msk < 16; msk <<= 1)
                #pragma unroll
                for (int r = 0; r < 4; ++r) {
                    s1[r] += __shfl_xor(s1[r], msk);
                    s2[r] += __shfl_xor(s2[r], msk);
                }
            if (l15 == 0) {
                #pragma unroll
                for (int r = 0; r < 4; ++r) {
                    int u = (mw << 6) + (mi << 4) + (quad << 2) + r;
                    red2[u * 8 + nq * 2 + 0] = s1[r];
                    red2[u * 8 + nq * 2 + 1] = s2[r];
                }
            }
        }
        __syncthreads();
        #pragma unroll
        for (int mi = 0; mi < 4; ++mi)
            #pragma unroll
            for (int r = 0; r < 4; ++r) {
                int u = (mw << 6) + (mi << 4) + (quad << 2) + r;
                float sum = red2[u * 8 + 0] + red2[u * 8 + 2] + red2[u * 8 + 4] + red2[u * 8 + 6];
                float sq  = red2[u * 8 + 1] + red2[u * 8 + 3] + red2[u * 8 + 5] + red2[u * 8 + 7];
                float mu = sum * (1.0f / 256.0f);
                float var = sq * (1.0f / 256.0f) - mu * mu;
                float rstd = rsqrtf(var + 1e-5f);
                #pragma unroll
                for (int nt = 0; nt < 4; ++nt) {
                    int j = (nq << 6) + (nt << 4) + l15;
                    Ob[(size_t)u * Ee + j] = (acc[mi][nt][r] - mu) * rstd * w2l[nt] + b2l[nt];
                }
            }
    }
}

extern "C" void kernel_launch(void* const* d_in, const int* in_sizes, int n_in,
                              void* d_out, int out_size, void* d_ws, size_t ws_size,
                              hipStream_t stream) {
    const float* Q    = (const float*)d_in[0];
    const float* K    = (const float*)d_in[1];
    const float* V    = (const float*)d_in[2];
    const float* M    = (const float*)d_in[3];
    const float* W1   = (const float*)d_in[4];
    const float* b1   = (const float*)d_in[5];
    const float* W2   = (const float*)d_in[6];
    const float* b2   = (const float*)d_in[7];
    const float* ln1w = (const float*)d_in[8];
    const float* ln1b = (const float*)d_in[9];
    const float* ln2w = (const float*)d_in[10];
    const float* ln2b = (const float*)d_in[11];
    float* out = (float*)d_out;

    if (ws_size >= WS_NEED_BYTES) {
        unsigned short* ws = (unsigned short*)d_ws;
        cvt_kernel<<<3032, 256, 0, stream>>>(Q, K, V, W1, W2, ws);
        attn_bf_kernel<<<Bsz * Tt * Dd, 512, 0, stream>>>(Q, M, ln1w, ln1b, ws);
        ffn_bf_kernel<<<(Bsz * Tt * Dd * Uu) / FFN_BM, 512, 0, stream>>>(b1, b2, ln2w, ln2b,
                                                                         ws, out);
    } else {
        int use_ws = (ws_size >= 262144) ? 1 : 0;
        const unsigned short* wsbf = (const unsigned short*)d_ws;
        if (use_ws) {
            convert_w_kernel<<<64, 256, 0, stream>>>(W1, W2, (unsigned short*)d_ws);
        }
        attn_kernel<<<Bsz * Tt * Dd, 512, 0, stream>>>(Q, K, V, M, ln1w, ln1b, out);
        ffn_kernel<<<(Bsz * Tt * Dd * Uu) / FFN_BM, 512, 0, stream>>>(W1, b1, W2, b2, ln2w, ln2b,
                                                                      wsbf, use_ws, out);
    }
}

// Round 7
// 540.977 us; speedup vs baseline: 1.2622x; 1.0381x over previous
//
#include <hip/hip_runtime.h>
#include <math.h>

#define Bsz 32
#define Tt  10
#define Dd  10
#define Uu  50
#define Pp  50
#define Ee  256

typedef __attribute__((ext_vector_type(8))) short bf16x8;   // MFMA A/B frag
typedef __attribute__((ext_vector_type(4))) float f32x4;    // MFMA C/D frag

#define STH 264   // row stride (halfwords) for 256-col LDS tiles: 16B rows, /8 odd
#define STV 72    // sVt row stride
#define STS 72    // sS row stride

// kernel1 (attention) LDS: sVt 256x72x2=36864 | sS 64x72x2=9216 | red 1024
#define K1_OFF_V 0
#define K1_OFF_S 36864
#define K1_OFF_R 46080
#define K1_SMEM  47104   // 3 blocks/CU

// kernel2 fast (FFN, BM=64): sX 64x264x2=33792 | sH 64x264x2=33792 | red2 2048
#define K3_OFF_X 0
#define K3_OFF_H 33792
#define K3_OFF_R 67584
#define K3_SMEM  69632   // 2 blocks/CU (139,264 <= 163,840)
#define FFN_BM2 64

// kernel2 fallback (round-5 verified, BM=128): sH 128x264x2=67584 | red2 4096
#define K2_OFF_H 0
#define K2_OFF_R 67584
#define K2_SMEM  71680
#define FFN_BM 128

// bf16 workspace layout (ushort element offsets)
#define WS_Q   0
#define WS_K   4096000
#define WS_V   8192000
#define WS_W1  12288000
#define WS_W2  12353536
#define WS_X   12419072
#define WS_NEED_BYTES 106758144ull   // (WS_X + 160000*256) * 2

__device__ __forceinline__ unsigned short f2bf(float f) {      // RNE fp32->bf16
    unsigned u = __builtin_bit_cast(unsigned, f);
    u += 0x7fffu + ((u >> 16) & 1u);
    return (unsigned short)(u >> 16);
}
__device__ __forceinline__ float bf2f(unsigned short h) {
    unsigned u = ((unsigned)h) << 16;
    return __builtin_bit_cast(float, u);
}
// A/B fragment from LDS: lane q*16+l15 -> row r0+l15, cols c0+q*8..+7 (b128)
__device__ __forceinline__ bf16x8 ldfrag(const unsigned short* p, int stride, int r0, int c0, int lane) {
    return *(const bf16x8*)(p + (size_t)(r0 + (lane & 15)) * stride + c0 + ((lane >> 4) << 3));
}
// fragment from global bf16 row-major [row][256]; optional clamp at 49
__device__ __forceinline__ bf16x8 bffrag(const unsigned short* __restrict__ base, int n, int k0, int lane) {
    const int row = n + (lane & 15);
    return *(const bf16x8*)(base + (size_t)row * 256 + k0 + ((lane >> 4) << 3));
}
__device__ __forceinline__ bf16x8 bffrag49(const unsigned short* __restrict__ base, int n, int k0, int lane) {
    int row = n + (lane & 15);
    row = row > 49 ? 49 : row;
    return *(const bf16x8*)(base + (size_t)row * 256 + k0 + ((lane >> 4) << 3));
}
// ---------- legacy fp32 helpers (fallback path) ----------
__device__ __forceinline__ bf16x8 gfrag49(const float* __restrict__ base, int n, int k0, int lane) {
    int row = n + (lane & 15);
    row = row > 49 ? 49 : row;
    const int col = k0 + ((lane >> 4) << 3);
    const float4 a = *(const float4*)(base + (size_t)row * 256 + col);
    const float4 b = *(const float4*)(base + (size_t)row * 256 + col + 4);
    bf16x8 r;
    r[0] = (short)f2bf(a.x); r[1] = (short)f2bf(a.y); r[2] = (short)f2bf(a.z); r[3] = (short)f2bf(a.w);
    r[4] = (short)f2bf(b.x); r[5] = (short)f2bf(b.y); r[6] = (short)f2bf(b.z); r[7] = (short)f2bf(b.w);
    return r;
}
__device__ __forceinline__ bf16x8 xfrag(const float* __restrict__ base, int n, int k0, int lane) {
    const int row = n + (lane & 15);
    const int col = k0 + ((lane >> 4) << 3);
    const float4 a = *(const float4*)(base + (size_t)row * 256 + col);
    const float4 b = *(const float4*)(base + (size_t)row * 256 + col + 4);
    bf16x8 r;
    r[0] = (short)f2bf(a.x); r[1] = (short)f2bf(a.y); r[2] = (short)f2bf(a.z); r[3] = (short)f2bf(a.w);
    r[4] = (short)f2bf(b.x); r[5] = (short)f2bf(b.y); r[6] = (short)f2bf(b.z); r[7] = (short)f2bf(b.w);
    return r;
}
__device__ __forceinline__ bf16x8 wfrag(const unsigned short* wbf, const float* wf, int use_ws,
                                        int n, int k0, int lane) {
    const int row = n + (lane & 15);
    const int col = k0 + ((lane >> 4) << 3);
    if (use_ws) {
        return *(const bf16x8*)(wbf + (size_t)row * 256 + col);
    }
    const float4 a = *(const float4*)(wf + (size_t)row * 256 + col);
    const float4 b = *(const float4*)(wf + (size_t)row * 256 + col + 4);
    bf16x8 r;
    r[0] = (short)f2bf(a.x); r[1] = (short)f2bf(a.y); r[2] = (short)f2bf(a.z); r[3] = (short)f2bf(a.w);
    r[4] = (short)f2bf(b.x); r[5] = (short)f2bf(b.y); r[6] = (short)f2bf(b.z); r[7] = (short)f2bf(b.w);
    return r;
}

// ===================== bf16 pre-convert: Q,K,V,W1,W2 -> ws ======================
__global__ __launch_bounds__(256) void cvt_kernel(
    const float* __restrict__ Q, const float* __restrict__ K, const float* __restrict__ V,
    const float* __restrict__ W1, const float* __restrict__ W2, unsigned short* __restrict__ ws)
{
    const int blk = blockIdx.x, t = threadIdx.x;
    const float* src; unsigned short* dst; int f4base;
    if (blk < 1000)      { src = Q;  dst = ws + WS_Q;  f4base = blk * 1024; }
    else if (blk < 2000) { src = K;  dst = ws + WS_K;  f4base = (blk - 1000) * 1024; }
    else if (blk < 3000) { src = V;  dst = ws + WS_V;  f4base = (blk - 2000) * 1024; }
    else if (blk < 3016) { src = W1; dst = ws + WS_W1; f4base = (blk - 3000) * 1024; }
    else                 { src = W2; dst = ws + WS_W2; f4base = (blk - 3016) * 1024; }
    #pragma unroll
    for (int j = 0; j < 4; ++j) {
        int i4 = f4base + t + j * 256;
        float4 v = *(const float4*)(src + (size_t)i4 * 4);
        ushort4 o; o.x = f2bf(v.x); o.y = f2bf(v.y); o.z = f2bf(v.z); o.w = f2bf(v.w);
        *(ushort4*)(dst + (size_t)i4 * 4) = o;
    }
}

__global__ void convert_w_kernel(const float* __restrict__ W1, const float* __restrict__ W2,
                                 unsigned short* __restrict__ ws) {
    int i4 = (blockIdx.x * 256 + threadIdx.x) * 4;
    float4 a = *(const float4*)(W1 + i4);
    ushort4 oa; oa.x = f2bf(a.x); oa.y = f2bf(a.y); oa.z = f2bf(a.z); oa.w = f2bf(a.w);
    *(ushort4*)(ws + i4) = oa;
    float4 b = *(const float4*)(W2 + i4);
    ushort4 ob; ob.x = f2bf(b.x); ob.y = f2bf(b.y); ob.z = f2bf(b.z); ob.w = f2bf(b.w);
    *(ushort4*)(ws + 65536 + i4) = ob;
}

// ===================== Kernel 1 (fast): attention + LN1 -> X bf16 in ws =====================
__global__ __launch_bounds__(512, 4) void attn_bf_kernel(
    const float* __restrict__ Q, const float* __restrict__ Msk,
    const float* __restrict__ ln1w, const float* __restrict__ ln1b,
    unsigned short* __restrict__ ws)
{
    __shared__ __align__(16) unsigned char smem[K1_SMEM];
    unsigned short* sVt = (unsigned short*)(smem + K1_OFF_V);
    unsigned short* sS  = (unsigned short*)(smem + K1_OFF_S);
    float*          red = (float*)(smem + K1_OFF_R);

    const int tid  = threadIdx.x;
    const int lane = tid & 63;
    const int wave = tid >> 6;
    const int quad = lane >> 4;
    const int l15  = lane & 15;

    const int btd = ((blockIdx.x & 7) * 400) + (blockIdx.x >> 3);
    const int b   = btd / (Tt * Dd);
    const int rem = btd % (Tt * Dd);
    const int t   = rem / Dd;
    const int d   = rem % Dd;

    const float* Qb = Q + ((size_t)(b * Tt + t) * Uu) * Ee;
    const unsigned short* Qbf = ws + WS_Q + (size_t)(b * Tt + t) * Uu * Ee;
    const unsigned short* Kbf = ws + WS_K + (size_t)(b * Dd + d) * Pp * Ee;
    const unsigned short* Vbf = ws + WS_V + (size_t)(b * Dd + d) * Pp * Ee;
    const float* Mb = Msk + ((size_t)((b * Tt + t) * Dd + d) * Uu) * Pp;
    unsigned short* Xbf = ws + WS_X + (size_t)btd * Uu * Ee;

    if (wave < 4) {
        const int mt = wave;
        int arow = mt * 16 + l15; if (arow > 49) arow = 49;
        const unsigned short* qrow = Qbf + (size_t)arow * Ee + (quad << 3);
        f32x4 acc[4];
        #pragma unroll
        for (int i = 0; i < 4; ++i) acc[i] = (f32x4){0.f, 0.f, 0.f, 0.f};
        #pragma unroll
        for (int k0 = 0; k0 < 256; k0 += 32) {
            bf16x8 a = *(const bf16x8*)(qrow + k0);
            #pragma unroll
            for (int nt = 0; nt < 4; ++nt) {
                bf16x8 bf = bffrag49(Kbf, nt << 4, k0, lane);
                acc[nt] = __builtin_amdgcn_mfma_f32_16x16x32_bf16(a, bf, acc[nt], 0, 0, 0);
            }
        }
        float l[4][4];
        #pragma unroll
        for (int nt = 0; nt < 4; ++nt) {
            int p = (nt << 4) + l15;
            #pragma unroll
            for (int r = 0; r < 4; ++r) {
                int u = mt * 16 + (quad << 2) + r;
                float v = acc[nt][r] * 0.0625f;
                if (p < Pp) { if (u < Uu) v += Mb[u * Pp + p]; }
                else v = -1e30f;
                l[nt][r] = v;
            }
        }
        #pragma unroll
        for (int r = 0; r < 4; ++r) {
            float m = fmaxf(fmaxf(l[0][r], l[1][r]), fmaxf(l[2][r], l[3][r]));
            #pragma unroll
            for (int msk = 1; msk < 16; msk <<= 1) m = fmaxf(m, __shfl_xor(m, msk));
            float e0 = __expf(l[0][r] - m), e1 = __expf(l[1][r] - m);
            float e2 = __expf(l[2][r] - m), e3 = __expf(l[3][r] - m);
            float s = e0 + e1 + e2 + e3;
            #pragma unroll
            for (int msk = 1; msk < 16; msk <<= 1) s += __shfl_xor(s, msk);
            float inv = 1.0f / s;
            int u = mt * 16 + (quad << 2) + r;
            sS[u * STS +  0 + l15] = f2bf(e0 * inv);
            sS[u * STS + 16 + l15] = f2bf(e1 * inv);
            sS[u * STS + 32 + l15] = f2bf(e2 * inv);
            sS[u * STS + 48 + l15] = f2bf(e3 * inv);
        }
    } else {
        const int lt = tid - 256;
        for (int i = lt; i < 1600; i += 256) {        // 50 p-rows x 32 e-chunks
            int p = i >> 5, e8 = (i & 31) << 3;
            bf16x8 v8 = *(const bf16x8*)(Vbf + (size_t)p * Ee + e8);
            #pragma unroll
            for (int j = 0; j < 8; ++j) sVt[(e8 + j) * STV + p] = (unsigned short)v8[j];
        }
        for (int i = lt; i < 3584; i += 256) {        // zero k-pad cols p=50..63
            int p = 50 + (i >> 8), e = i & 255;
            sVt[e * STV + p] = 0;
        }
    }
    __syncthreads();   // B1: sS + sVt ready

    {
        const int mt = wave >> 1;
        const int nh = (wave & 1) << 7;
        f32x4 acc[8];
        #pragma unroll
        for (int i = 0; i < 8; ++i) acc[i] = (f32x4){0.f, 0.f, 0.f, 0.f};
        #pragma unroll
        for (int k0 = 0; k0 < 64; k0 += 32) {
            bf16x8 a = ldfrag(sS, STS, mt << 4, k0, lane);
            #pragma unroll
            for (int nt = 0; nt < 8; ++nt) {
                bf16x8 bf = ldfrag(sVt, STV, nh + (nt << 4), k0, lane);
                acc[nt] = __builtin_amdgcn_mfma_f32_16x16x32_bf16(a, bf, acc[nt], 0, 0, 0);
            }
        }
        float s1[4] = {0.f, 0.f, 0.f, 0.f}, s2[4] = {0.f, 0.f, 0.f, 0.f};
        #pragma unroll
        for (int nt = 0; nt < 8; ++nt) {
            int e = nh + (nt << 4) + l15;
            #pragma unroll
            for (int r = 0; r < 4; ++r) {
                int u = (mt << 4) + (quad << 2) + r;
                float x = 0.f;
                if (u < Uu) x = acc[nt][r] + Qb[(size_t)u * Ee + e];
                acc[nt][r] = x;
                s1[r] += x; s2[r] += x * x;
            }
        }
        #pragma unroll
        for (int msk = 1; msk < 16; msk <<= 1) {
            #pragma unroll
            for (int r = 0; r < 4; ++r) { s1[r] += __shfl_xor(s1[r], msk); s2[r] += __shfl_xor(s2[r], msk); }
        }
        if (l15 == 0) {
            #pragma unroll
            for (int r = 0; r < 4; ++r) {
                int u = (mt << 4) + (quad << 2) + r;
                red[u * 4 + (wave & 1) * 2 + 0] = s1[r];
                red[u * 4 + (wave & 1) * 2 + 1] = s2[r];
            }
        }
        __syncthreads();   // B2
        #pragma unroll
        for (int r = 0; r < 4; ++r) {
            int u = (mt << 4) + (quad << 2) + r;
            if (u < Uu) {
                float sum = red[u * 4 + 0] + red[u * 4 + 2];
                float sq  = red[u * 4 + 1] + red[u * 4 + 3];
                float mu = sum * (1.0f / 256.0f);
                float var = sq * (1.0f / 256.0f) - mu * mu;
                float rstd = rsqrtf(var + 1e-5f);
                #pragma unroll
                for (int nt = 0; nt < 8; ++nt) {
                    int e = nh + (nt << 4) + l15;
                    Xbf[(size_t)u * Ee + e] = f2bf((acc[nt][r] - mu) * rstd * ln1w[e] + ln1b[e]);
                }
            }
        }
    }
}

// ===================== Kernel 2 (fast v3): FFN + LN2; X tile staged in LDS =====================
// BM=64 (grid 2500, all rows real). 8 waves = 2 row-halves x 4 col-quarters; 2x4 frags/wave.
// sX staged once (32 KB, stride 264 -> 2-way-free); A-frags + residual from LDS; W from L2.
__global__ __launch_bounds__(512, 4) void ffn_bf_kernel(
    const float* __restrict__ b1, const float* __restrict__ b2,
    const float* __restrict__ ln2w, const float* __restrict__ ln2b,
    const unsigned short* __restrict__ ws, float* __restrict__ out)
{
    __shared__ __align__(16) unsigned char smem[K3_SMEM];
    unsigned short* sX   = (unsigned short*)(smem + K3_OFF_X);
    unsigned short* sH   = (unsigned short*)(smem + K3_OFF_H);
    float*          red2 = (float*)(smem + K3_OFF_R);   // [u][nq][2], u in 0..63

    const int tid  = threadIdx.x;
    const int lane = tid & 63;
    const int wave = tid >> 6;
    const int quad = lane >> 4;
    const int l15  = lane & 15;

    const int mw = wave >> 2;     // 0..1: row-half (rows mw*32 .. +31)
    const int nq = wave & 3;      // 0..3: col-quarter (cols nq*64 .. +63)

    const size_t rowbase = (size_t)blockIdx.x * FFN_BM2;
    const unsigned short* Xbf  = ws + WS_X + rowbase * Ee;
    const unsigned short* W1bf = ws + WS_W1;
    const unsigned short* W2bf = ws + WS_W2;
    float* Ob = out + rowbase * Ee;

    // ---- Stage X tile (64x256 bf16 = 2048 x 16B chunks; 4 per thread, coalesced) ----
    {
        bf16x8 st[4];
        #pragma unroll
        for (int i = 0; i < 4; ++i) {
            int idx = tid + (i << 9);                 // 0..2047
            int r = idx >> 5, c8 = (idx & 31) << 3;   // 32 chunks per row
            st[i] = *(const bf16x8*)(Xbf + (size_t)r * Ee + c8);
        }
        #pragma unroll
        for (int i = 0; i < 4; ++i) {
            int idx = tid + (i << 9);
            int r = idx >> 5, c8 = (idx & 31) << 3;
            *(bf16x8*)(sX + r * STH + c8) = st[i];
        }
    }
    __syncthreads();   // B1: sX ready

    // ---- FFN1: H = relu(X.W1^T + b1); A from LDS, W from L2; H -> LDS ----
    {
        f32x4 acc[2][4];
        #pragma unroll
        for (int mi = 0; mi < 2; ++mi)
            #pragma unroll
            for (int nt = 0; nt < 4; ++nt) acc[mi][nt] = (f32x4){0.f, 0.f, 0.f, 0.f};
        float b1v[4];
        #pragma unroll
        for (int nt = 0; nt < 4; ++nt) b1v[nt] = b1[(nq << 6) + (nt << 4) + l15];
        #pragma unroll
        for (int k0 = 0; k0 < 256; k0 += 32) {
            bf16x8 a0 = ldfrag(sX, STH, (mw << 5),      k0, lane);
            bf16x8 a1 = ldfrag(sX, STH, (mw << 5) + 16, k0, lane);
            #pragma unroll
            for (int nt = 0; nt < 4; ++nt) {
                bf16x8 bf = bffrag(W1bf, (nq << 6) + (nt << 4), k0, lane);
                acc[0][nt] = __builtin_amdgcn_mfma_f32_16x16x32_bf16(a0, bf, acc[0][nt], 0, 0, 0);
                acc[1][nt] = __builtin_amdgcn_mfma_f32_16x16x32_bf16(a1, bf, acc[1][nt], 0, 0, 0);
            }
        }
        #pragma unroll
        for (int mi = 0; mi < 2; ++mi)
            #pragma unroll
            for (int nt = 0; nt < 4; ++nt) {
                int j = (nq << 6) + (nt << 4) + l15;
                #pragma unroll
                for (int r = 0; r < 4; ++r) {
                    int u = (mw << 5) + (mi << 4) + (quad << 2) + r;
                    sH[u * STH + j] = f2bf(fmaxf(acc[mi][nt][r] + b1v[nt], 0.f));
                }
            }
    }
    __syncthreads();   // B2: sH ready

    // ---- FFN2: Y = H.W2^T + b2 + X(LDS); LN2; store ----
    {
        f32x4 acc[2][4];
        #pragma unroll
        for (int mi = 0; mi < 2; ++mi)
            #pragma unroll
            for (int nt = 0; nt < 4; ++nt) acc[mi][nt] = (f32x4){0.f, 0.f, 0.f, 0.f};
        float b2v[4], w2l[4], b2l[4];
        #pragma unroll
        for (int nt = 0; nt < 4; ++nt) {
            int j = (nq << 6) + (nt << 4) + l15;
            b2v[nt] = b2[j]; w2l[nt] = ln2w[j]; b2l[nt] = ln2b[j];
        }
        #pragma unroll
        for (int k0 = 0; k0 < 256; k0 += 32) {
            bf16x8 a0 = ldfrag(sH, STH, (mw << 5),      k0, lane);
            bf16x8 a1 = ldfrag(sH, STH, (mw << 5) + 16, k0, lane);
            #pragma unroll
            for (int nt = 0; nt < 4; ++nt) {
                bf16x8 bf = bffrag(W2bf, (nq << 6) + (nt << 4), k0, lane);
                acc[0][nt] = __builtin_amdgcn_mfma_f32_16x16x32_bf16(a0, bf, acc[0][nt], 0, 0, 0);
                acc[1][nt] = __builtin_amdgcn_mfma_f32_16x16x32_bf16(a1, bf, acc[1][nt], 0, 0, 0);
            }
        }
        #pragma unroll
        for (int mi = 0; mi < 2; ++mi) {
            float s1[4] = {0.f, 0.f, 0.f, 0.f}, s2[4] = {0.f, 0.f, 0.f, 0.f};
            #pragma unroll
            for (int nt = 0; nt < 4; ++nt) {
                int j = (nq << 6) + (nt << 4) + l15;
                #pragma unroll
                for (int r = 0; r < 4; ++r) {
                    int u = (mw << 5) + (mi << 4) + (quad << 2) + r;
                    float y = acc[mi][nt][r] + b2v[nt] + bf2f(sX[u * STH + j]);   // resid from LDS
                    acc[mi][nt][r] = y;
                    s1[r] += y; s2[r] += y * y;
                }
            }
            #pragma unroll
            for (int msk = 1; msk < 16; msk <<= 1)
                #pragma unroll
                for (int r = 0; r < 4; ++r) {
                    s1[r] += __shfl_xor(s1[r], msk);
                    s2[r] += __shfl_xor(s2[r], msk);
                }
            if (l15 == 0) {
                #pragma unroll
                for (int r = 0; r < 4; ++r) {
                    int u = (mw << 5) + (mi << 4) + (quad << 2) + r;
                    red2[u * 8 + nq * 2 + 0] = s1[r];
                    red2[u * 8 + nq * 2 + 1] = s2[r];
                }
            }
        }
        __syncthreads();   // B3: red2 ready
        #pragma unroll
        for (int mi = 0; mi < 2; ++mi)
            #pragma unroll
            for (int r = 0; r < 4; ++r) {
                int u = (mw << 5) + (mi << 4) + (quad << 2) + r;
                float sum = red2[u * 8 + 0] + red2[u * 8 + 2] + red2[u * 8 + 4] + red2[u * 8 + 6];
                float sq  = red2[u * 8 + 1] + red2[u * 8 + 3] + red2[u * 8 + 5] + red2[u * 8 + 7];
                float mu = sum * (1.0f / 256.0f);
                float var = sq * (1.0f / 256.0f) - mu * mu;
                float rstd = rsqrtf(var + 1e-5f);
                #pragma unroll
                for (int nt = 0; nt < 4; ++nt) {
                    int j = (nq << 6) + (nt << 4) + l15;
                    Ob[(size_t)u * Ee + j] = (acc[mi][nt][r] - mu) * rstd * w2l[nt] + b2l[nt];
                }
            }
    }
}

// ===================== Fallback kernels (round-5, verified) =====================
__global__ __launch_bounds__(512, 4) void attn_kernel(
    const float* __restrict__ Q,  const float* __restrict__ K,
    const float* __restrict__ V,  const float* __restrict__ Msk,
    const float* __restrict__ ln1w, const float* __restrict__ ln1b,
    float* __restrict__ out)
{
    __shared__ __align__(16) unsigned char smem[K1_SMEM];
    unsigned short* sVt = (unsigned short*)(smem + K1_OFF_V);
    unsigned short* sS  = (unsigned short*)(smem + K1_OFF_S);
    float*          red = (float*)(smem + K1_OFF_R);

    const int tid  = threadIdx.x;
    const int lane = tid & 63;
    const int wave = tid >> 6;
    const int quad = lane >> 4;
    const int l15  = lane & 15;

    const int btd = ((blockIdx.x & 7) * 400) + (blockIdx.x >> 3);
    const int b   = btd / (Tt * Dd);
    const int rem = btd % (Tt * Dd);
    const int t   = rem / Dd;
    const int d   = rem % Dd;

    const float* Qb = Q + ((size_t)(b * Tt + t) * Uu) * Ee;
    const float* Kb = K + ((size_t)(b * Dd + d) * Pp) * Ee;
    const float* Vb = V + ((size_t)(b * Dd + d) * Pp) * Ee;
    const float* Mb = Msk + ((size_t)((b * Tt + t) * Dd + d) * Uu) * Pp;
    float*       Xb = out + ((size_t)btd * Uu) * Ee;

    if (wave < 4) {
        const int mt = wave;
        int arow = mt * 16 + l15; if (arow > 49) arow = 49;
        const float* qrow = Qb + (size_t)arow * Ee + (quad << 3);
        f32x4 acc[4];
        #pragma unroll
        for (int i = 0; i < 4; ++i) acc[i] = (f32x4){0.f, 0.f, 0.f, 0.f};
        #pragma unroll
        for (int k0 = 0; k0 < 256; k0 += 32) {
            float4 qa = *(const float4*)(qrow + k0);
            float4 qb = *(const float4*)(qrow + k0 + 4);
            bf16x8 a;
            a[0] = (short)f2bf(qa.x); a[1] = (short)f2bf(qa.y); a[2] = (short)f2bf(qa.z); a[3] = (short)f2bf(qa.w);
            a[4] = (short)f2bf(qb.x); a[5] = (short)f2bf(qb.y); a[6] = (short)f2bf(qb.z); a[7] = (short)f2bf(qb.w);
            #pragma unroll
            for (int nt = 0; nt < 4; ++nt) {
                bf16x8 bf = gfrag49(Kb, nt << 4, k0, lane);
                acc[nt] = __builtin_amdgcn_mfma_f32_16x16x32_bf16(a, bf, acc[nt], 0, 0, 0);
            }
        }
        float l[4][4];
        #pragma unroll
        for (int nt = 0; nt < 4; ++nt) {
            int p = (nt << 4) + l15;
            #pragma unroll
            for (int r = 0; r < 4; ++r) {
                int u = mt * 16 + (quad << 2) + r;
                float v = acc[nt][r] * 0.0625f;
                if (p < Pp) { if (u < Uu) v += Mb[u * Pp + p]; }
                else v = -1e30f;
                l[nt][r] = v;
            }
        }
        #pragma unroll
        for (int r = 0; r < 4; ++r) {
            float m = fmaxf(fmaxf(l[0][r], l[1][r]), fmaxf(l[2][r], l[3][r]));
            #pragma unroll
            for (int msk = 1; msk < 16; msk <<= 1) m = fmaxf(m, __shfl_xor(m, msk));
            float e0 = __expf(l[0][r] - m), e1 = __expf(l[1][r] - m);
            float e2 = __expf(l[2][r] - m), e3 = __expf(l[3][r] - m);
            float s = e0 + e1 + e2 + e3;
            #pragma unroll
            for (int msk = 1; msk < 16; msk <<= 1) s += __shfl_xor(s, msk);
            float inv = 1.0f / s;
            int u = mt * 16 + (quad << 2) + r;
            sS[u * STS +  0 + l15] = f2bf(e0 * inv);
            sS[u * STS + 16 + l15] = f2bf(e1 * inv);
            sS[u * STS + 32 + l15] = f2bf(e2 * inv);
            sS[u * STS + 48 + l15] = f2bf(e3 * inv);
        }
    } else {
        const int lt = tid - 256;
        #pragma unroll 4
        for (int i = lt; i < 12800; i += 256) {
            int p = i >> 8, e = i & 255;
            sVt[e * STV + p] = f2bf(Vb[p * Ee + e]);
        }
        for (int i = lt; i < 3584; i += 256) {
            int p = 50 + (i >> 8), e = i & 255;
            sVt[e * STV + p] = 0;
        }
    }
    __syncthreads();

    {
        const int mt = wave >> 1;
        const int nh = (wave & 1) << 7;
        f32x4 acc[8];
        #pragma unroll
        for (int i = 0; i < 8; ++i) acc[i] = (f32x4){0.f, 0.f, 0.f, 0.f};
        #pragma unroll
        for (int k0 = 0; k0 < 64; k0 += 32) {
            bf16x8 a = ldfrag(sS, STS, mt << 4, k0, lane);
            #pragma unroll
            for (int nt = 0; nt < 8; ++nt) {
                bf16x8 bf = ldfrag(sVt, STV, nh + (nt << 4), k0, lane);
                acc[nt] = __builtin_amdgcn_mfma_f32_16x16x32_bf16(a, bf, acc[nt], 0, 0, 0);
            }
        }
        float s1[4] = {0.f, 0.f, 0.f, 0.f}, s2[4] = {0.f, 0.f, 0.f, 0.f};
        #pragma unroll
        for (int nt = 0; nt < 8; ++nt) {
            int e = nh + (nt << 4) + l15;
            #pragma unroll
            for (int r = 0; r < 4; ++r) {
                int u = (mt << 4) + (quad << 2) + r;
                float x = 0.f;
                if (u < Uu) x = acc[nt][r] + Qb[(size_t)u * Ee + e];
                acc[nt][r] = x;
                s1[r] += x; s2[r] += x * x;
            }
        }
        #pragma unroll
        for (int msk = 1; msk < 16; msk <<= 1) {
            #pragma unroll
            for (int r = 0; r < 4; ++r) { s1[r] += __shfl_xor(s1[r], msk); s2[r] += __shfl_xor(s2[r], msk); }
        }
        if (l15 == 0) {
            #pragma unroll
            for (int r = 0; r < 4; ++r) {
                int u = (mt << 4) + (quad << 2) + r;
                red[u * 4 + (wave & 1) * 2 + 0] = s1[r];
                red[u * 4 + (wave & 1) * 2 + 1] = s2[r];
            }
        }
        __syncthreads();
        #pragma unroll
        for (int r = 0; r < 4; ++r) {
            int u = (mt << 4) + (quad << 2) + r;
            if (u < Uu) {
                float sum = red[u * 4 + 0] + red[u * 4 + 2];
                float sq  = red[u * 4 + 1] + red[u * 4 + 3];
                float mu = sum * (1.0f / 256.0f);
                float var = sq * (1.0f / 256.0f) - mu * mu;
                float rstd = rsqrtf(var + 1e-5f);
                #pragma unroll
                for (int nt = 0; nt < 8; ++nt) {
                    int e = nh + (nt << 4) + l15;
                    Xb[(size_t)u * Ee + e] = (acc[nt][r] - mu) * rstd * ln1w[e] + ln1b[e];
                }
            }
        }
    }
}

__global__ __launch_bounds__(512, 4) void ffn_kernel(
    const float* __restrict__ W1, const float* __restrict__ b1,
    const float* __restrict__ W2, const float* __restrict__ b2,
    const float* __restrict__ ln2w, const float* __restrict__ ln2b,
    const unsigned short* __restrict__ wsbf, int use_ws,
    float* __restrict__ out)
{
    __shared__ __align__(16) unsigned char smem[K2_SMEM];
    unsigned short* sH   = (unsigned short*)(smem + K2_OFF_H);
    float*          red2 = (float*)(smem + K2_OFF_R);

    const int tid  = threadIdx.x;
    const int lane = tid & 63;
    const int wave = tid >> 6;
    const int quad = lane >> 4;
    const int l15  = lane & 15;

    const int mw = wave >> 2;
    const int nq = wave & 3;

    const size_t rowbase = (size_t)blockIdx.x * FFN_BM;
    const float* Xb = out + rowbase * Ee;
    float*       Ob = out + rowbase * Ee;

    {
        f32x4 acc[4][4];
        #pragma unroll
        for (int mi = 0; mi < 4; ++mi)
            #pragma unroll
            for (int nt = 0; nt < 4; ++nt) acc[mi][nt] = (f32x4){0.f, 0.f, 0.f, 0.f};
        float b1v[4];
        #pragma unroll
        for (int nt = 0; nt < 4; ++nt) b1v[nt] = b1[(nq << 6) + (nt << 4) + l15];
        #pragma unroll
        for (int k0 = 0; k0 < 256; k0 += 32) {
            bf16x8 a[4];
            #pragma unroll
            for (int mi = 0; mi < 4; ++mi) a[mi] = xfrag(Xb, (mw << 6) + (mi << 4), k0, lane);
            #pragma unroll
            for (int nt = 0; nt < 4; ++nt) {
                bf16x8 bf = wfrag(wsbf, W1, use_ws, (nq << 6) + (nt << 4), k0, lane);
                #pragma unroll
                for (int mi = 0; mi < 4; ++mi)
                    acc[mi][nt] = __builtin_amdgcn_mfma_f32_16x16x32_bf16(a[mi], bf, acc[mi][nt], 0, 0, 0);
            }
        }
        #pragma unroll
        for (int mi = 0; mi < 4; ++mi)
            #pragma unroll
            for (int nt = 0; nt < 4; ++nt) {
                int j = (nq << 6) + (nt << 4) + l15;
                #pragma unroll
                for (int r = 0; r < 4; ++r) {
                    int u = (mw << 6) + (mi << 4) + (quad << 2) + r;
                    sH[u * STH + j] = f2bf(fmaxf(acc[mi][nt][r] + b1v[nt], 0.f));
                }
            }
    }
    __syncthreads();

    {
        f32x4 acc[4][4];
        #pragma unroll
        for (int mi = 0; mi < 4; ++mi)
            #pragma unroll
            for (int nt = 0; nt < 4; ++nt) acc[mi][nt] = (f32x4){0.f, 0.f, 0.f, 0.f};
        float b2v[4], w2l[4], b2l[4];
        #pragma unroll
        for (int nt = 0; nt < 4; ++nt) {
            int j = (nq << 6) + (nt << 4) + l15;
            b2v[nt] = b2[j]; w2l[nt] = ln2w[j]; b2l[nt] = ln2b[j];
        }
        #pragma unroll
        for (int k0 = 0; k0 < 256; k0 += 32) {
            bf16x8 a[4];
            #pragma unroll
            for (int mi = 0; mi < 4; ++mi) a[mi] = ldfrag(sH, STH, (mw << 6) + (mi << 4), k0, lane);
            #pragma unroll
            for (int nt = 0; nt < 4; ++nt) {
                bf16x8 bf = wfrag(wsbf + 65536, W2, use_ws, (nq << 6) + (nt << 4), k0, lane);
                #pragma unroll
                for (int mi = 0; mi < 4; ++mi)
                    acc[mi][nt] = __builtin_amdgcn_mfma_f32_16x16x32_bf16(a[mi], bf, acc[mi][nt], 0, 0, 0);
            }
        }
        #pragma unroll
        for (int mi = 0; mi < 4; ++mi) {
            float s1[4] = {0.f, 0.f, 0.f, 0.f}, s2[4] = {0.f, 0.f, 0.f, 0.f};
            #pragma unroll
            for (int nt = 0; nt < 4; ++nt) {
                int j = (nq << 6) + (nt << 4) + l15;
                #pragma unroll
                for (int r = 0; r < 4; ++r) {
                    int u = (mw << 6) + (mi << 4) + (quad << 2) + r;
                    float y = acc[mi][nt][r] + b2v[nt] + Xb[(size_t)u * Ee + j];
                    acc[mi][nt][r] = y;
                    s1[r] += y; s2[r] += y * y;
                }
            }
            #pragma unroll
            for (int msk = 1; msk < 16; msk <<= 1)
                #pragma unroll
                for (int r = 0; r < 4; ++r) {
                    s1[r] += __shfl_xor(s1[r], msk);
                    s2[r] += __shfl_xor(s2[r], msk);
                }
            if (l15 == 0) {
                #pragma unroll
                for (int r = 0; r < 4; ++r) {
                    int u = (mw << 6) + (mi << 4) + (quad << 2) + r;
                    red2[u * 8 + nq * 2 + 0] = s1[r];
                    red2[u * 8 + nq * 2 + 1] = s2[r];
                }
            }
        }
        __syncthreads();
        #pragma unroll
        for (int mi = 0; mi < 4; ++mi)
            #pragma unroll
            for (int r = 0; r < 4; ++r) {
                int u = (mw << 6) + (mi << 4) + (quad << 2) + r;
                float sum = red2[u * 8 + 0] + red2[u * 8 + 2] + red2[u * 8 + 4] + red2[u * 8 + 6];
                float sq  = red2[u * 8 + 1] + red2[u * 8 + 3] + red2[u * 8 + 5] + red2[u * 8 + 7];
                float mu = sum * (1.0f / 256.0f);
                float var = sq * (1.0f / 256.0f) - mu * mu;
                float rstd = rsqrtf(var + 1e-5f);
                #pragma unroll
                for (int nt = 0; nt < 4; ++nt) {
                    int j = (nq << 6) + (nt << 4) + l15;
                    Ob[(size_t)u * Ee + j] = (acc[mi][nt][r] - mu) * rstd * w2l[nt] + b2l[nt];
                }
            }
    }
}

extern "C" void kernel_launch(void* const* d_in, const int* in_sizes, int n_in,
                              void* d_out, int out_size, void* d_ws, size_t ws_size,
                              hipStream_t stream) {
    const float* Q    = (const float*)d_in[0];
    const float* K    = (const float*)d_in[1];
    const float* V    = (const float*)d_in[2];
    const float* M    = (const float*)d_in[3];
    const float* W1   = (const float*)d_in[4];
    const float* b1   = (const float*)d_in[5];
    const float* W2   = (const float*)d_in[6];
    const float* b2   = (const float*)d_in[7];
    const float* ln1w = (const float*)d_in[8];
    const float* ln1b = (const float*)d_in[9];
    const float* ln2w = (const float*)d_in[10];
    const float* ln2b = (const float*)d_in[11];
    float* out = (float*)d_out;

    if (ws_size >= WS_NEED_BYTES) {
        unsigned short* ws = (unsigned short*)d_ws;
        cvt_kernel<<<3032, 256, 0, stream>>>(Q, K, V, W1, W2, ws);
        attn_bf_kernel<<<Bsz * Tt * Dd, 512, 0, stream>>>(Q, M, ln1w, ln1b, ws);
        ffn_bf_kernel<<<(Bsz * Tt * Dd * Uu) / FFN_BM2, 512, 0, stream>>>(b1, b2, ln2w, ln2b,
                                                                          ws, out);
    } else {
        int use_ws = (ws_size >= 262144) ? 1 : 0;
        const unsigned short* wsbf = (const unsigned short*)d_ws;
        if (use_ws) {
            convert_w_kernel<<<64, 256, 0, stream>>>(W1, W2, (unsigned short*)d_ws);
        }
        attn_kernel<<<Bsz * Tt * Dd, 512, 0, stream>>>(Q, K, V, M, ln1w, ln1b, out);
        ffn_kernel<<<(Bsz * Tt * Dd * Uu) / FFN_BM, 512, 0, stream>>>(W1, b1, W2, b2, ln2w, ln2b,
                                                                      wsbf, use_ws, out);
    }
}